// Round 6
// baseline (239.936 us; speedup 1.0000x reference)
//
#include <hip/hip_runtime.h>
#include <hip/hip_cooperative_groups.h>

namespace cg = cooperative_groups;

#define NB    16
#define CIN   16
#define COUT  32
#define DIN   32
#define DOUT  30
#define NTILE 1920           // 8 htiles x 15 d2 x 16 b
#define CGRID 640            // 1920/640 = 3 tiles per block, <=3 blocks/CU co-resident

typedef __attribute__((ext_vector_type(8)))  short  short8;
typedef __attribute__((ext_vector_type(16))) float  f32x16;

static __device__ __forceinline__ unsigned short f2bf_rne(float f) {
    unsigned int u = __builtin_bit_cast(unsigned int, f);
    u += 0x7fffu + ((u >> 16) & 1u);
    return (unsigned short)(u >> 16);
}
static __device__ __forceinline__ float bf2f(unsigned short s) {
    unsigned int u = ((unsigned int)s) << 16;
    return __builtin_bit_cast(float, u);
}

// ---------------- cooperative single kernel ----------------
// Phase 1: repack W (Cout,Cin,3,3,3 fp32) into bf16 hi/lo A-fragments in ws (55 KB, L2-hot).
// grid.sync()
// Phase 2: each block loops 3 tiles (tile = 4h x 2d x 32co x 30w): stage x-tile
// (4 planes x 6 rows, split bf16 hi/lo, coalesced) into 48 KB LDS, 162 MFMAs/wave,
// fused epilogue. No early returns (barriers must stay uniform).
__global__ __launch_bounds__(256, 3) void conv_coop(
    const float* __restrict__ x,
    const float* __restrict__ wgt,
    const float* __restrict__ cbias,
    const float* __restrict__ scal,
    const float* __restrict__ bpar,
    float* __restrict__ out,
    short* __restrict__ wsA)
{
    __shared__ __align__(16) short sx[24576];   // 24 slot-pairs x (hi,lo) x 512 shorts = 48 KB
    __shared__ float sp[96];

    const int tid  = threadIdx.x;
    const int wy   = tid >> 6;
    const int lane = tid & 63;

    if (tid < 32) {
        sp[tid]      = cbias[tid];
        sp[32 + tid] = scal[tid];
        sp[64 + tid] = bpar[tid];
    }

    // ---- phase 1: W-fragment table (1728 entries; entry i = s*64+l) ----
    const int gtid = blockIdx.x * 256 + tid;
    if (gtid < 1728) {
        const int s = gtid >> 6, l = gtid & 63;
        const int co = l & 31, ci0 = (l >> 5) * 8;
        short8 vh, vl;
#pragma unroll
        for (int j = 0; j < 8; ++j) {
            float f = wgt[co * (CIN * 27) + (ci0 + j) * 27 + s];
            unsigned short hb = f2bf_rne(f);
            vh[j] = (short)hb;
            vl[j] = (short)f2bf_rne(f - bf2f(hb));
        }
        ((short8*)wsA)[s * 64 + l]        = vh;
        ((short8*)wsA)[1728 + s * 64 + l] = vl;
    }

    cg::this_grid().sync();

    const short8* wa = (const short8*)wsA;

    // ---- phase 2: 3 tiles per block ----
    for (int t = blockIdx.x; t < NTILE; t += CGRID) {
        const int b  = t / 120;
        const int r0 = t - b * 120;
        const int d2 = r0 >> 3;          // 0..14
        const int ht = r0 & 7;           // 0..7
        const int h0 = ht * 4, d0 = d2 * 2;

        __syncthreads();   // previous tile's LDS readers done before we overwrite

        // stage x-tile: unit c = (pr, w, oc); pr = p*6+row (p 0..3, row 0..5)
        for (int c = tid; c < 1536; c += 256) {
            const int oc = c & 1;
            const int q  = c >> 1;
            const int w  = q & 31;
            const int pr = q >> 5;                 // 0..23
            const int p  = pr / 6, row = pr - p * 6;
            int hin = h0 + row; if (hin > 31) hin = 31;   // htile-7 halo clamp, feeds masked rows
            const int din = d0 + p;                       // <= 31 always
            const float* xp = x + ((((b * 16 + oc * 8) * 32 + din) * 32 + hin) * 32 + w);
            short8 vh, vl;
#pragma unroll
            for (int j = 0; j < 8; ++j) {
                float f = xp[j * 32768];           // ci = oc*8 + j
                unsigned short hb = f2bf_rne(f);
                vh[j] = (short)hb;
                vl[j] = (short)f2bf_rne(f - bf2f(hb));
            }
            *(short8*)(sx + (pr * 2 + 0) * 512 + w * 16 + oc * 8) = vh;
            *(short8*)(sx + (pr * 2 + 1) * 512 + w * 16 + oc * 8) = vl;
        }
        __syncthreads();

        const int h = h0 + wy;
        if (h < DOUT) {                 // wave-uniform; no barriers inside
            const int n  = lane & 31;
            const int oc = lane >> 5;
            int cofs[3];
#pragma unroll
            for (int kw = 0; kw < 3; ++kw) {
                int wc = n + kw; if (wc > 31) wc = 31;
                cofs[kw] = wc * 16 + oc * 8;
            }

            f32x16 acc0, acc1;
#pragma unroll
            for (int i = 0; i < 16; ++i) { acc0[i] = 0.0f; acc1[i] = 0.0f; }

#pragma unroll
            for (int kh = 0; kh < 3; ++kh) {
                const int rowi = wy + kh;
#pragma unroll
                for (int kw = 0; kw < 3; ++kw) {
                    short8 bh[4], bl[4];
#pragma unroll
                    for (int p = 0; p < 4; ++p) {      // planes d0..d0+3, reused across kd
                        const short* slot = sx + ((p * 6 + rowi) * 2) * 512;
                        bh[p] = *(const short8*)(slot + cofs[kw]);
                        bl[p] = *(const short8*)(slot + 512 + cofs[kw]);
                    }
#pragma unroll
                    for (int kd = 0; kd < 3; ++kd) {
                        const int s = kd * 9 + kh * 3 + kw;
                        short8 ah = wa[s * 64 + lane];
                        short8 al = wa[1728 + s * 64 + lane];
                        acc0 = __builtin_amdgcn_mfma_f32_32x32x16_bf16(ah, bh[kd],     acc0, 0, 0, 0);
                        acc1 = __builtin_amdgcn_mfma_f32_32x32x16_bf16(ah, bh[kd + 1], acc1, 0, 0, 0);
                        acc0 = __builtin_amdgcn_mfma_f32_32x32x16_bf16(ah, bl[kd],     acc0, 0, 0, 0);
                        acc1 = __builtin_amdgcn_mfma_f32_32x32x16_bf16(ah, bl[kd + 1], acc1, 0, 0, 0);
                        acc0 = __builtin_amdgcn_mfma_f32_32x32x16_bf16(al, bh[kd],     acc0, 0, 0, 0);
                        acc1 = __builtin_amdgcn_mfma_f32_32x32x16_bf16(al, bh[kd + 1], acc1, 0, 0, 0);
                    }
                }
            }

            if (n < DOUT) {
                const int ob = b * (COUT * 27000) + h * 30 + n;
#pragma unroll
                for (int rr = 0; rr < 16; ++rr) {
                    const int co = (rr & 3) + 8 * (rr >> 2) + 4 * oc;
                    float y0 = acc0[rr] + sp[co];
                    float t0 = y0 * sp[32 + co];
                    float th0 = 1.0f - 2.0f / (__expf(2.0f * t0) + 1.0f);
                    float z0 = th0 * sp[64 + co];
                    out[ob + co * 27000 + d0 * 900] = 1.0f / (1.0f + __expf(-z0));
                    float y1 = acc1[rr] + sp[co];
                    float t1 = y1 * sp[32 + co];
                    float th1 = 1.0f - 2.0f / (__expf(2.0f * t1) + 1.0f);
                    float z1 = th1 * sp[64 + co];
                    out[ob + co * 27000 + (d0 + 1) * 900] = 1.0f / (1.0f + __expf(-z1));
                }
            }
        }
    }
}

// ================= fallback: round-4 verified 2-kernel path =================
#define XS_OFF 57344

__global__ __launch_bounds__(256) void prep_kernel(const float* __restrict__ x,
                                                   const float* __restrict__ wgt,
                                                   char* __restrict__ ws) {
    const int bx  = blockIdx.x;
    const int tid = threadIdx.x;
    if (bx < 4096) {
        const int wy = tid >> 6, lane = tid & 63;
        const int rid = bx * 4 + wy;
        const int h = rid & 31, d = (rid >> 5) & 31, b = rid >> 10;
        const int w = lane >> 1, oc = lane & 1;
        const float* xp = x + ((((size_t)(b * 16 + oc * 8) * 32 + d) * 32 + h) * 32 + w);
        short8 vh, vl;
#pragma unroll
        for (int j = 0; j < 8; ++j) {
            float f = xp[j * 32768];
            unsigned short hb = f2bf_rne(f);
            vh[j] = (short)hb;
            vl[j] = (short)f2bf_rne(f - bf2f(hb));
        }
        char* row = ws + XS_OFF + (size_t)rid * 2048;
        *(short8*)(row + lane * 16)        = vh;
        *(short8*)(row + 1024 + lane * 16) = vl;
    } else if (tid < 64) {
        const int s = bx - 4096;
        const int l = tid;
        const int co = l & 31, ci0 = (l >> 5) * 8;
        short8 vh, vl;
#pragma unroll
        for (int j = 0; j < 8; ++j) {
            float f = wgt[co * (CIN * 27) + (ci0 + j) * 27 + s];
            unsigned short hb = f2bf_rne(f);
            vh[j] = (short)hb;
            vl[j] = (short)f2bf_rne(f - bf2f(hb));
        }
        ((short8*)ws)[s * 64 + l]        = vh;
        ((short8*)ws)[1728 + s * 64 + l] = vl;
    }
}

__global__ __launch_bounds__(256) void conv_main(
    const char* __restrict__ ws,
    const float* __restrict__ cbias,
    const float* __restrict__ scal,
    const float* __restrict__ bpar,
    float* __restrict__ out)
{
    __shared__ __align__(16) short sx[24576];
    __shared__ float sp[96];
    const int htile = blockIdx.x, d2 = blockIdx.y, b = blockIdx.z;
    const int tid = threadIdx.x, wy = tid >> 6, lane = tid & 63;
    if (tid < 32) { sp[tid] = cbias[tid]; sp[32 + tid] = scal[tid]; sp[64 + tid] = bpar[tid]; }
    const int h0 = htile * 4, d0 = d2 * 2;
    const char* xbase = ws + XS_OFF;
    const int psw = lane * 8;
#pragma unroll
    for (int r = wy * 12; r < wy * 12 + 12; ++r) {
        const int buf = r & 1, pr = r >> 1;
        const int p = pr / 6, row = pr - p * 6;
        int hin = h0 + row; if (hin > 31) hin = 31;
        const int rid = (b * 32 + d0 + p) * 32 + hin;
        const short8 v = *((const short8*)(xbase + (size_t)rid * 2048 + buf * 1024) + lane);
        *(short8*)(sx + (pr * 2 + buf) * 512 + psw) = v;
    }
    __syncthreads();
    const int h = h0 + wy;
    if (h >= DOUT) return;
    const int n = lane & 31, oc = lane >> 5;
    int cofs[3];
#pragma unroll
    for (int kw = 0; kw < 3; ++kw) {
        int wc = n + kw; if (wc > 31) wc = 31;
        cofs[kw] = (2 * wc + oc) * 8;
    }
    f32x16 acc0, acc1;
#pragma unroll
    for (int i = 0; i < 16; ++i) { acc0[i] = 0.0f; acc1[i] = 0.0f; }
    const short8* wa = (const short8*)ws;
#pragma unroll
    for (int kh = 0; kh < 3; ++kh) {
        const int rowi = wy + kh;
#pragma unroll
        for (int kw = 0; kw < 3; ++kw) {
            short8 bh[4], bl[4];
#pragma unroll
            for (int p = 0; p < 4; ++p) {
                const short* slot = sx + ((p * 6 + rowi) * 2) * 512;
                bh[p] = *(const short8*)(slot + cofs[kw]);
                bl[p] = *(const short8*)(slot + 512 + cofs[kw]);
            }
#pragma unroll
            for (int kd = 0; kd < 3; ++kd) {
                const int s = kd * 9 + kh * 3 + kw;
                short8 ah = wa[s * 64 + lane];
                short8 al = wa[1728 + s * 64 + lane];
                acc0 = __builtin_amdgcn_mfma_f32_32x32x16_bf16(ah, bh[kd],     acc0, 0, 0, 0);
                acc1 = __builtin_amdgcn_mfma_f32_32x32x16_bf16(ah, bh[kd + 1], acc1, 0, 0, 0);
                acc0 = __builtin_amdgcn_mfma_f32_32x32x16_bf16(ah, bl[kd],     acc0, 0, 0, 0);
                acc1 = __builtin_amdgcn_mfma_f32_32x32x16_bf16(ah, bl[kd + 1], acc1, 0, 0, 0);
                acc0 = __builtin_amdgcn_mfma_f32_32x32x16_bf16(al, bh[kd],     acc0, 0, 0, 0);
                acc1 = __builtin_amdgcn_mfma_f32_32x32x16_bf16(al, bh[kd + 1], acc1, 0, 0, 0);
            }
        }
    }
    if (n < DOUT) {
        const int ob = b * (COUT * 27000) + h * 30 + n;
#pragma unroll
        for (int r = 0; r < 16; ++r) {
            const int co = (r & 3) + 8 * (r >> 2) + 4 * oc;
            float y0 = acc0[r] + sp[co];
            float t0 = y0 * sp[32 + co];
            float th0 = 1.0f - 2.0f / (__expf(2.0f * t0) + 1.0f);
            float z0 = th0 * sp[64 + co];
            out[ob + co * 27000 + d0 * 900] = 1.0f / (1.0f + __expf(-z0));
            float y1 = acc1[r] + sp[co];
            float t1 = y1 * sp[32 + co];
            float th1 = 1.0f - 2.0f / (__expf(2.0f * t1) + 1.0f);
            float z1 = th1 * sp[64 + co];
            out[ob + co * 27000 + (d0 + 1) * 900] = 1.0f / (1.0f + __expf(-z1));
        }
    }
}

// last-resort direct conv (no ws)
__global__ __launch_bounds__(256) void conv3d_direct_fb(
    const float* __restrict__ x, const float* __restrict__ wgt,
    const float* __restrict__ cbias, const float* __restrict__ scal,
    const float* __restrict__ bpar, float* __restrict__ out)
{
    __shared__ float sw[CIN * 27];
    const int bx = blockIdx.x, co = blockIdx.y, b = blockIdx.z;
    const int tid = threadIdx.y * 32 + threadIdx.x;
    for (int i = tid; i < CIN * 27; i += 256) sw[i] = wgt[co * (CIN * 27) + i];
    __syncthreads();
    const float bias = cbias[co], s = scal[co], bp = bpar[co];
    const int dt = bx & 7, ht = bx >> 3;
    const int d0 = dt * 4, h = ht * 8 + threadIdx.y, w = threadIdx.x;
    if (w >= DOUT || h >= DOUT) return;
    int rowoff[6];
#pragma unroll
    for (int dz = 0; dz < 6; ++dz) { int dd = d0 + dz; if (dd > 31) dd = 31; rowoff[dz] = dd * 1024; }
    float acc[4] = {0.f, 0.f, 0.f, 0.f};
    const int xb = b * (CIN * 32768);
    for (int ci = 0; ci < CIN; ++ci) {
        const int cioff = xb + ci * 32768;
        const float* swc = &sw[ci * 27];
#pragma unroll
        for (int kh = 0; kh < 3; ++kh) {
            const int hbase = cioff + (h + kh) * DIN + w;
#pragma unroll
            for (int kw = 0; kw < 3; ++kw) {
                float xv[6];
#pragma unroll
                for (int dz = 0; dz < 6; ++dz) xv[dz] = x[hbase + kw + rowoff[dz]];
#pragma unroll
                for (int kd = 0; kd < 3; ++kd) {
                    const float wv = swc[(kd * 3 + kh) * 3 + kw];
#pragma unroll
                    for (int dd = 0; dd < 4; ++dd) acc[dd] = fmaf(xv[dd + kd], wv, acc[dd]);
                }
            }
        }
    }
    const int obase = (b * COUT + co) * 27000 + h * 30 + w;
#pragma unroll
    for (int dd = 0; dd < 4; ++dd) {
        const int d = d0 + dd;
        if (d < DOUT) {
            float y = acc[dd] + bias;
            float t = y * s;
            float th = 1.0f - 2.0f / (__expf(2.0f * t) + 1.0f);
            float z = th * bp;
            out[obase + d * 900] = 1.0f / (1.0f + __expf(-z));
        }
    }
}

extern "C" void kernel_launch(void* const* d_in, const int* in_sizes, int n_in,
                              void* d_out, int out_size, void* d_ws, size_t ws_size,
                              hipStream_t stream) {
    const float* x     = (const float*)d_in[0];
    const float* wgt   = (const float*)d_in[1];
    const float* cbias = (const float*)d_in[2];
    const float* scal  = (const float*)d_in[3];
    const float* bpar  = (const float*)d_in[4];
    float* out = (float*)d_out;

    // Primary: single cooperative kernel (needs 55296 B of ws for the W-frag table).
    if (ws_size >= 55296) {
        short* wsA = (short*)d_ws;
        void* args[] = {(void*)&x, (void*)&wgt, (void*)&cbias, (void*)&scal,
                        (void*)&bpar, (void*)&out, (void*)&wsA};
        hipError_t err = hipLaunchCooperativeKernel((const void*)conv_coop,
                                                    dim3(CGRID), dim3(256),
                                                    args, 0, stream);
        if (err == hipSuccess) return;
        (void)hipGetLastError();   // clear error state before fallback
    }
    // Fallback: round-4 verified 2-kernel path.
    const size_t need_full = (size_t)XS_OFF + (size_t)16384 * 2048;
    if (ws_size >= need_full) {
        char* ws = (char*)d_ws;
        hipLaunchKernelGGL(prep_kernel, dim3(4096 + 27), dim3(256), 0, stream, x, wgt, ws);
        hipLaunchKernelGGL(conv_main, dim3(8, 15, NB), dim3(256), 0, stream,
                           ws, cbias, scal, bpar, out);
    } else {
        hipLaunchKernelGGL(conv3d_direct_fb, dim3(32, COUT, NB), dim3(32, 8), 0, stream,
                           x, wgt, cbias, scal, bpar, out);
    }
}

// Round 7
// 161.158 us; speedup vs baseline: 1.4888x; 1.4888x over previous
//
#include <hip/hip_runtime.h>

#define NB    16
#define CIN   16
#define COUT  32
#define DIN   32
#define DOUT  30

typedef __attribute__((ext_vector_type(8)))  short  short8;
typedef __attribute__((ext_vector_type(16))) float  f32x16;

static __device__ __forceinline__ unsigned short f2bf_rne(float f) {
    unsigned int u = __builtin_bit_cast(unsigned int, f);
    u += 0x7fffu + ((u >> 16) & 1u);
    return (unsigned short)(u >> 16);
}
static __device__ __forceinline__ float bf2f(unsigned short s) {
    unsigned int u = ((unsigned int)s) << 16;
    return __builtin_bit_cast(float, u);
}

// ---- dynamic-LDS layout (short offsets) ----
// SWH [0,13824)        : W-frag hi (1728 entries x 8 shorts)         27.6 KB
// SWL [13824,27648)    : W-frag lo                                   27.6 KB
// SX  [27648,70656)    : x-tile, 42 slot-pairs (7 planes x 6 rows),
//                        each pair = hi 512 + lo 512 shorts          86.0 KB
// sp  at byte 141312   : 96 floats                                    0.4 KB
#define SWH 0
#define SWL 13824
#define SX  27648
#define SP_BYTE 141312
#define LDS_BYTES 141696

// ---------------- single self-contained kernel ----------------
// Grid (htile 0..7, dtile 0..5, b): 768 threads = 12 waves (3/SIMD), 1 block/CU,
// exactly 3 serial rounds per CU. Per block: build W-frag table + x-tile in LDS
// (one barrier), then wave wy (hrow=wy&3, dq=wy>>2) computes output rows
// h=4*htile+hrow for d-outs d0+2*dq (+1 if dq<2), all 32 co. A and B fragments
// both from LDS; 1620 MFMAs (32x32x16 bf16) per block; fused epilogue.
__global__ __launch_bounds__(768, 1) void conv_mono(
    const float* __restrict__ x,
    const float* __restrict__ wgt,
    const float* __restrict__ cbias,
    const float* __restrict__ scal,
    const float* __restrict__ bpar,
    float* __restrict__ out)
{
    extern __shared__ __align__(16) char smem_raw[];
    short* sm = (short*)smem_raw;
    float* sp = (float*)(smem_raw + SP_BYTE);

    const int htile = blockIdx.x;   // 0..7  -> h0 = 4*htile
    const int dtile = blockIdx.y;   // 0..5  -> d0 = 5*dtile (outs d0..d0+4)
    const int b     = blockIdx.z;

    const int tid  = threadIdx.x;
    const int wy   = tid >> 6;      // 0..11
    const int lane = tid & 63;

    if (tid < 32) {
        sp[tid]      = cbias[tid];
        sp[32 + tid] = scal[tid];
        sp[64 + tid] = bpar[tid];
    }

    const int h0 = htile * 4, d0 = dtile * 5;

    // ---- W-fragment table: entry i = s*64+l; lane l holds A[co=l&31][ci=(l>>5)*8+j] ----
    for (int i = tid; i < 1728; i += 768) {
        const int s = i >> 6, l = i & 63;
        const int co = l & 31, ci0 = (l >> 5) * 8;
        short8 vh, vl;
#pragma unroll
        for (int j = 0; j < 8; ++j) {
            float f = wgt[co * (CIN * 27) + (ci0 + j) * 27 + s];
            unsigned short hb = f2bf_rne(f);
            vh[j] = (short)hb;
            vl[j] = (short)f2bf_rne(f - bf2f(hb));
        }
        *(short8*)(sm + SWH + i * 8) = vh;
        *(short8*)(sm + SWL + i * 8) = vl;
    }

    // ---- x-tile: 7 planes (d0..d0+6) x 6 rows (h0..h0+5); slot pr=p*6+r,
    //      pair = hi 512 + lo 512 shorts, within slot [w 32][ci 16] ----
    for (int c = tid; c < 2688; c += 768) {
        const int oc = c & 1;
        const int q  = c >> 1;
        const int w  = q & 31;
        const int pr = q >> 5;                 // 0..41
        const int p  = pr / 6, r = pr - p * 6;
        int hin = h0 + r; if (hin > 31) hin = 31;   // htile-7 halo clamp (feeds masked rows)
        const int din = d0 + p;                     // <= 31 always (25+6=31)
        const float* xp = x + ((((b * 16 + oc * 8) * 32 + din) * 32 + hin) * 32 + w);
        short8 vh, vl;
#pragma unroll
        for (int j = 0; j < 8; ++j) {
            float f = xp[j * 32768];           // ci = oc*8 + j
            unsigned short hb = f2bf_rne(f);
            vh[j] = (short)hb;
            vl[j] = (short)f2bf_rne(f - bf2f(hb));
        }
        *(short8*)(sm + SX + pr * 1024 +       w * 16 + oc * 8) = vh;
        *(short8*)(sm + SX + pr * 1024 + 512 + w * 16 + oc * 8) = vl;
    }
    __syncthreads();   // single barrier in kernel

    const int hrow = wy & 3, dq = wy >> 2;     // dq 0,1: 2 d-outs; dq 2: 1 d-out
    const int h = h0 + hrow;
    if (h >= DOUT) return;                     // wave-uniform, after the only barrier

    const int n   = lane & 31;                 // output w (30 valid + 2 pad)
    const int oc2 = lane >> 5;                 // ci octet
    const int pbase = dq * 2;
    const int da = d0 + pbase;                 // first d-out of this wave

    int cofs[3];
#pragma unroll
    for (int kw = 0; kw < 3; ++kw) {
        int wc = n + kw; if (wc > 31) wc = 31;
        cofs[kw] = wc * 16 + oc2 * 8;
    }

    f32x16 acc0, acc1;
#pragma unroll
    for (int i = 0; i < 16; ++i) { acc0[i] = 0.0f; acc1[i] = 0.0f; }

    if (dq < 2) {
        // ---- 2 d-outs: planes pbase..pbase+3 ----
#pragma unroll
        for (int kh = 0; kh < 3; ++kh) {
            const int rowi = hrow + kh;
#pragma unroll
            for (int kw = 0; kw < 3; ++kw) {
                short8 bh[4], bl[4];
#pragma unroll
                for (int q = 0; q < 4; ++q) {
                    const int base = SX + ((pbase + q) * 6 + rowi) * 1024;
                    bh[q] = *(const short8*)(sm + base + cofs[kw]);
                    bl[q] = *(const short8*)(sm + base + 512 + cofs[kw]);
                }
#pragma unroll
                for (int kd = 0; kd < 3; ++kd) {
                    const int s = kd * 9 + kh * 3 + kw;
                    short8 ah = *(const short8*)(sm + SWH + (s * 64 + lane) * 8);
                    short8 al = *(const short8*)(sm + SWL + (s * 64 + lane) * 8);
                    acc0 = __builtin_amdgcn_mfma_f32_32x32x16_bf16(ah, bh[kd],     acc0, 0, 0, 0);
                    acc1 = __builtin_amdgcn_mfma_f32_32x32x16_bf16(ah, bh[kd + 1], acc1, 0, 0, 0);
                    acc0 = __builtin_amdgcn_mfma_f32_32x32x16_bf16(ah, bl[kd],     acc0, 0, 0, 0);
                    acc1 = __builtin_amdgcn_mfma_f32_32x32x16_bf16(ah, bl[kd + 1], acc1, 0, 0, 0);
                    acc0 = __builtin_amdgcn_mfma_f32_32x32x16_bf16(al, bh[kd],     acc0, 0, 0, 0);
                    acc1 = __builtin_amdgcn_mfma_f32_32x32x16_bf16(al, bh[kd + 1], acc1, 0, 0, 0);
                }
            }
        }
    } else {
        // ---- 1 d-out: planes pbase..pbase+2 (pbase=4 -> planes 4..6) ----
#pragma unroll
        for (int kh = 0; kh < 3; ++kh) {
            const int rowi = hrow + kh;
#pragma unroll
            for (int kw = 0; kw < 3; ++kw) {
                short8 bh[3], bl[3];
#pragma unroll
                for (int q = 0; q < 3; ++q) {
                    const int base = SX + ((pbase + q) * 6 + rowi) * 1024;
                    bh[q] = *(const short8*)(sm + base + cofs[kw]);
                    bl[q] = *(const short8*)(sm + base + 512 + cofs[kw]);
                }
#pragma unroll
                for (int kd = 0; kd < 3; ++kd) {
                    const int s = kd * 9 + kh * 3 + kw;
                    short8 ah = *(const short8*)(sm + SWH + (s * 64 + lane) * 8);
                    short8 al = *(const short8*)(sm + SWL + (s * 64 + lane) * 8);
                    acc0 = __builtin_amdgcn_mfma_f32_32x32x16_bf16(ah, bh[kd], acc0, 0, 0, 0);
                    acc0 = __builtin_amdgcn_mfma_f32_32x32x16_bf16(ah, bl[kd], acc0, 0, 0, 0);
                    acc0 = __builtin_amdgcn_mfma_f32_32x32x16_bf16(al, bh[kd], acc0, 0, 0, 0);
                }
            }
        }
    }

    // ---- epilogue: C/D map co=(r&3)+8*(r>>2)+4*oc2, col=n ----
    if (n < DOUT) {
        const int ob = b * (COUT * 27000) + h * 30 + n;
#pragma unroll
        for (int r = 0; r < 16; ++r) {
            const int co = (r & 3) + 8 * (r >> 2) + 4 * oc2;
            float y0 = acc0[r] + sp[co];
            float t0 = y0 * sp[32 + co];
            float th0 = 1.0f - 2.0f / (__expf(2.0f * t0) + 1.0f);
            float z0 = th0 * sp[64 + co];
            out[ob + co * 27000 + da * 900] = 1.0f / (1.0f + __expf(-z0));
            if (dq < 2) {
                float y1 = acc1[r] + sp[co];
                float t1 = y1 * sp[32 + co];
                float th1 = 1.0f - 2.0f / (__expf(2.0f * t1) + 1.0f);
                float z1 = th1 * sp[64 + co];
                out[ob + co * 27000 + (da + 1) * 900] = 1.0f / (1.0f + __expf(-z1));
            }
        }
    }
}

// ================= fallback: round-4 verified 2-kernel path =================
#define XS_OFF 57344

__global__ __launch_bounds__(256) void prep_kernel(const float* __restrict__ x,
                                                   const float* __restrict__ wgt,
                                                   char* __restrict__ ws) {
    const int bx  = blockIdx.x;
    const int tid = threadIdx.x;
    if (bx < 4096) {
        const int wy = tid >> 6, lane = tid & 63;
        const int rid = bx * 4 + wy;
        const int h = rid & 31, d = (rid >> 5) & 31, b = rid >> 10;
        const int w = lane >> 1, oc = lane & 1;
        const float* xp = x + ((((size_t)(b * 16 + oc * 8) * 32 + d) * 32 + h) * 32 + w);
        short8 vh, vl;
#pragma unroll
        for (int j = 0; j < 8; ++j) {
            float f = xp[j * 32768];
            unsigned short hb = f2bf_rne(f);
            vh[j] = (short)hb;
            vl[j] = (short)f2bf_rne(f - bf2f(hb));
        }
        char* row = ws + XS_OFF + (size_t)rid * 2048;
        *(short8*)(row + lane * 16)        = vh;
        *(short8*)(row + 1024 + lane * 16) = vl;
    } else if (tid < 64) {
        const int s = bx - 4096;
        const int l = tid;
        const int co = l & 31, ci0 = (l >> 5) * 8;
        short8 vh, vl;
#pragma unroll
        for (int j = 0; j < 8; ++j) {
            float f = wgt[co * (CIN * 27) + (ci0 + j) * 27 + s];
            unsigned short hb = f2bf_rne(f);
            vh[j] = (short)hb;
            vl[j] = (short)f2bf_rne(f - bf2f(hb));
        }
        ((short8*)ws)[s * 64 + l]        = vh;
        ((short8*)ws)[1728 + s * 64 + l] = vl;
    }
}

__global__ __launch_bounds__(256) void conv_main(
    const char* __restrict__ ws,
    const float* __restrict__ cbias,
    const float* __restrict__ scal,
    const float* __restrict__ bpar,
    float* __restrict__ out)
{
    __shared__ __align__(16) short sx[24576];
    __shared__ float sp[96];
    const int htile = blockIdx.x, d2 = blockIdx.y, b = blockIdx.z;
    const int tid = threadIdx.x, wy = tid >> 6, lane = tid & 63;
    if (tid < 32) { sp[tid] = cbias[tid]; sp[32 + tid] = scal[tid]; sp[64 + tid] = bpar[tid]; }
    const int h0 = htile * 4, d0 = d2 * 2;
    const char* xbase = ws + XS_OFF;
    const int psw = lane * 8;
#pragma unroll
    for (int r = wy * 12; r < wy * 12 + 12; ++r) {
        const int buf = r & 1, pr = r >> 1;
        const int p = pr / 6, row = pr - p * 6;
        int hin = h0 + row; if (hin > 31) hin = 31;
        const int rid = (b * 32 + d0 + p) * 32 + hin;
        const short8 v = *((const short8*)(xbase + (size_t)rid * 2048 + buf * 1024) + lane);
        *(short8*)(sx + (pr * 2 + buf) * 512 + psw) = v;
    }
    __syncthreads();
    const int h = h0 + wy;
    if (h >= DOUT) return;
    const int n = lane & 31, oc = lane >> 5;
    int cofs[3];
#pragma unroll
    for (int kw = 0; kw < 3; ++kw) {
        int wc = n + kw; if (wc > 31) wc = 31;
        cofs[kw] = (2 * wc + oc) * 8;
    }
    f32x16 acc0, acc1;
#pragma unroll
    for (int i = 0; i < 16; ++i) { acc0[i] = 0.0f; acc1[i] = 0.0f; }
    const short8* wa = (const short8*)ws;
#pragma unroll
    for (int kh = 0; kh < 3; ++kh) {
        const int rowi = wy + kh;
#pragma unroll
        for (int kw = 0; kw < 3; ++kw) {
            short8 bh[4], bl[4];
#pragma unroll
            for (int p = 0; p < 4; ++p) {
                const short* slot = sx + ((p * 6 + rowi) * 2) * 512;
                bh[p] = *(const short8*)(slot + cofs[kw]);
                bl[p] = *(const short8*)(slot + 512 + cofs[kw]);
            }
#pragma unroll
            for (int kd = 0; kd < 3; ++kd) {
                const int s = kd * 9 + kh * 3 + kw;
                short8 ah = wa[s * 64 + lane];
                short8 al = wa[1728 + s * 64 + lane];
                acc0 = __builtin_amdgcn_mfma_f32_32x32x16_bf16(ah, bh[kd],     acc0, 0, 0, 0);
                acc1 = __builtin_amdgcn_mfma_f32_32x32x16_bf16(ah, bh[kd + 1], acc1, 0, 0, 0);
                acc0 = __builtin_amdgcn_mfma_f32_32x32x16_bf16(ah, bl[kd],     acc0, 0, 0, 0);
                acc1 = __builtin_amdgcn_mfma_f32_32x32x16_bf16(ah, bl[kd + 1], acc1, 0, 0, 0);
                acc0 = __builtin_amdgcn_mfma_f32_32x32x16_bf16(al, bh[kd],     acc0, 0, 0, 0);
                acc1 = __builtin_amdgcn_mfma_f32_32x32x16_bf16(al, bh[kd + 1], acc1, 0, 0, 0);
            }
        }
    }
    if (n < DOUT) {
        const int ob = b * (COUT * 27000) + h * 30 + n;
#pragma unroll
        for (int r = 0; r < 16; ++r) {
            const int co = (r & 3) + 8 * (r >> 2) + 4 * oc;
            float y0 = acc0[r] + sp[co];
            float t0 = y0 * sp[32 + co];
            float th0 = 1.0f - 2.0f / (__expf(2.0f * t0) + 1.0f);
            float z0 = th0 * sp[64 + co];
            out[ob + co * 27000 + d0 * 900] = 1.0f / (1.0f + __expf(-z0));
            float y1 = acc1[r] + sp[co];
            float t1 = y1 * sp[32 + co];
            float th1 = 1.0f - 2.0f / (__expf(2.0f * t1) + 1.0f);
            float z1 = th1 * sp[64 + co];
            out[ob + co * 27000 + (d0 + 1) * 900] = 1.0f / (1.0f + __expf(-z1));
        }
    }
}

// last-resort direct conv (no ws)
__global__ __launch_bounds__(256) void conv3d_direct_fb(
    const float* __restrict__ x, const float* __restrict__ wgt,
    const float* __restrict__ cbias, const float* __restrict__ scal,
    const float* __restrict__ bpar, float* __restrict__ out)
{
    __shared__ float sw[CIN * 27];
    const int bx = blockIdx.x, co = blockIdx.y, b = blockIdx.z;
    const int tid = threadIdx.y * 32 + threadIdx.x;
    for (int i = tid; i < CIN * 27; i += 256) sw[i] = wgt[co * (CIN * 27) + i];
    __syncthreads();
    const float bias = cbias[co], s = scal[co], bp = bpar[co];
    const int dt = bx & 7, ht = bx >> 3;
    const int d0 = dt * 4, h = ht * 8 + threadIdx.y, w = threadIdx.x;
    if (w >= DOUT || h >= DOUT) return;
    int rowoff[6];
#pragma unroll
    for (int dz = 0; dz < 6; ++dz) { int dd = d0 + dz; if (dd > 31) dd = 31; rowoff[dz] = dd * 1024; }
    float acc[4] = {0.f, 0.f, 0.f, 0.f};
    const int xb = b * (CIN * 32768);
    for (int ci = 0; ci < CIN; ++ci) {
        const int cioff = xb + ci * 32768;
        const float* swc = &sw[ci * 27];
#pragma unroll
        for (int kh = 0; kh < 3; ++kh) {
            const int hbase = cioff + (h + kh) * DIN + w;
#pragma unroll
            for (int kw = 0; kw < 3; ++kw) {
                float xv[6];
#pragma unroll
                for (int dz = 0; dz < 6; ++dz) xv[dz] = x[hbase + kw + rowoff[dz]];
#pragma unroll
                for (int kd = 0; kd < 3; ++kd) {
                    const float wv = swc[(kd * 3 + kh) * 3 + kw];
#pragma unroll
                    for (int dd = 0; dd < 4; ++dd) acc[dd] = fmaf(xv[dd + kd], wv, acc[dd]);
                }
            }
        }
    }
    const int obase = (b * COUT + co) * 27000 + h * 30 + w;
#pragma unroll
    for (int dd = 0; dd < 4; ++dd) {
        const int d = d0 + dd;
        if (d < DOUT) {
            float y = acc[dd] + bias;
            float t = y * s;
            float th = 1.0f - 2.0f / (__expf(2.0f * t) + 1.0f);
            float z = th * bp;
            out[obase + d * 900] = 1.0f / (1.0f + __expf(-z));
        }
    }
}

extern "C" void kernel_launch(void* const* d_in, const int* in_sizes, int n_in,
                              void* d_out, int out_size, void* d_ws, size_t ws_size,
                              hipStream_t stream) {
    const float* x     = (const float*)d_in[0];
    const float* wgt   = (const float*)d_in[1];
    const float* cbias = (const float*)d_in[2];
    const float* scal  = (const float*)d_in[3];
    const float* bpar  = (const float*)d_in[4];
    float* out = (float*)d_out;

    // Primary: single self-contained kernel, 141.7 KB dynamic LDS.
    hipError_t aerr = hipFuncSetAttribute((const void*)conv_mono,
                                          hipFuncAttributeMaxDynamicSharedMemorySize,
                                          LDS_BYTES);
    if (aerr == hipSuccess) {
        hipLaunchKernelGGL(conv_mono, dim3(8, 6, NB), dim3(768), LDS_BYTES, stream,
                           x, wgt, cbias, scal, bpar, out);
        if (hipGetLastError() == hipSuccess) return;
    }
    (void)hipGetLastError();
    // Fallback: round-4 verified 2-kernel path.
    const size_t need_full = (size_t)XS_OFF + (size_t)16384 * 2048;
    if (ws_size >= need_full) {
        char* ws = (char*)d_ws;
        hipLaunchKernelGGL(prep_kernel, dim3(4096 + 27), dim3(256), 0, stream, x, wgt, ws);
        hipLaunchKernelGGL(conv_main, dim3(8, 15, NB), dim3(256), 0, stream,
                           ws, cbias, scal, bpar, out);
    } else {
        hipLaunchKernelGGL(conv3d_direct_fb, dim3(32, COUT, NB), dim3(32, 8), 0, stream,
                           x, wgt, cbias, scal, bpar, out);
    }
}